// Round 2
// baseline (176.736 us; speedup 1.0000x reference)
//
#include <hip/hip_runtime.h>
#include <stdint.h>

// S4 layer, fused single-kernel version (R9b; R9 was a macro-hygiene compile
// fail: YST uses token TIL which YTILE's parameter does not substitute — the
// original kernel bound `const int TIL` around each YTILE call; restored).
// Evidence from R8 rocprof: top-5 dispatches are all harness poison fills
// (49-50us @ 84% HBM peak) => k_bx and k_rec_y are each <49us; dur_us is
// dominated by reset traffic + the 2-kernel structure. This round fuses
// bx-GEMM + recurrence + y-GEMM into ONE kernel: each wave (chunk c, batch b)
// computes its own 48-row bx tile via MFMA (identical math => bit-identical
// bf16 u values), stages it in LDS, runs the fp32 recurrence from LDS, then
// the y-GEMM. Removes: second launch, inter-kernel drain, 8.4MB bxh write +
// 12.6MB re-read. d_ws is now completely unused.
// LDS: 32KB B->C frag region (aliased, barrier-separated) + 27KB bx tiles +
// 18KB h tiles = 77KB static -> 2 blocks/CU (154KB of 160KB), 2 waves/SIMD.
#define SEQ  2048
#define NBAT 32
#define DIN  256
#define DOUT 256
#define LAT  64
#define CH   32
#define WARM 16

typedef __attribute__((ext_vector_type(8))) short short8;  // 8 x bf16
typedef __attribute__((ext_vector_type(4))) float f32x4;

__device__ __forceinline__ float bf2f(unsigned short u) {
  return __uint_as_float(((unsigned int)u) << 16);
}
__device__ __forceinline__ unsigned short f2bf(float f) {
  unsigned int u = __float_as_uint(f);
  u += 0x7fffu + ((u >> 16) & 1u);     // RNE
  return (unsigned short)(u >> 16);
}
__device__ __forceinline__ unsigned int pack2bf(float lo, float hi) {
  unsigned int a = __float_as_uint(lo);
  unsigned int b = __float_as_uint(hi);
  a += 0x7fffu + ((a >> 16) & 1u);
  b += 0x7fffu + ((b >> 16) & 1u);
  return (a >> 16) | (b & 0xffff0000u);
}

#define PACK8(DST, VA, VB) { \
    union { unsigned int u[4]; short8 s; } _r; \
    _r.u[0] = pack2bf((VA)[0], (VA)[1]); \
    _r.u[1] = pack2bf((VA)[2], (VA)[3]); \
    _r.u[2] = pack2bf((VB)[0], (VB)[1]); \
    _r.u[3] = pack2bf((VB)[2], (VB)[3]); \
    DST = _r.s; }

// ---- bx phase: one 16-row M-tile (rows = timesteps, fixed batch b) ----
// X[t][b][d] flat offset = t*8192 + b*256 + d. Same MFMA pattern as the
// verified k_bx (A-frag = X rows, B-frag = staged Bm frags), so u values are
// bit-identical to R8.
#define XDECL f32x4 x0a,x0b,x1a,x1b,x2a,x2b,x3a,x3b,x4a,x4b,x5a,x5b,x6a,x6b,x7a,x7b;
#define FXLD(K, MT) { \
    const float* _xp = X + (size_t)(base + (MT)*16 + m) * 8192 + b * 256 + (K)*32 + q*8; \
    x##K##a = *(const f32x4*)_xp;  x##K##b = *(const f32x4*)(_xp + 4); }
#define FBXK(K) { short8 _a; PACK8(_a, x##K##a, x##K##b); \
    short8 _b0 = *(const short8*)(Bl8 + ((K)*4+0)*512 + lane*8); \
    short8 _b1 = *(const short8*)(Bl8 + ((K)*4+1)*512 + lane*8); \
    short8 _b2 = *(const short8*)(Bl8 + ((K)*4+2)*512 + lane*8); \
    short8 _b3 = *(const short8*)(Bl8 + ((K)*4+3)*512 + lane*8); \
    acc0 = __builtin_amdgcn_mfma_f32_16x16x32_bf16(_a, _b0, acc0, 0, 0, 0); \
    acc1 = __builtin_amdgcn_mfma_f32_16x16x32_bf16(_a, _b1, acc1, 0, 0, 0); \
    acc2 = __builtin_amdgcn_mfma_f32_16x16x32_bf16(_a, _b2, acc2, 0, 0, 0); \
    acc3 = __builtin_amdgcn_mfma_f32_16x16x32_bf16(_a, _b3, acc3, 0, 0, 0); }
#define FTILE(MT) { \
    FXLD(0,MT) FXLD(1,MT) FXLD(2,MT) FXLD(3,MT) \
    FXLD(4,MT) FXLD(5,MT) FXLD(6,MT) FXLD(7,MT) \
    f32x4 acc0={0,0,0,0}, acc1={0,0,0,0}, acc2={0,0,0,0}, acc3={0,0,0,0}; \
    FBXK(0) FBXK(1) FBXK(2) FBXK(3) FBXK(4) FBXK(5) FBXK(6) FBXK(7) \
    _Pragma("unroll") \
    for (int r = 0; r < 4; ++r) { \
      unsigned short* _op = bxw + ((MT)*16 + q*4 + r) * 72 + m; \
      _op[ 0] = f2bf(acc0[r]);  _op[16] = f2bf(acc1[r]); \
      _op[32] = f2bf(acc2[r]);  _op[48] = f2bf(acc3[r]); } }

// ---- y phase (unchanged from verified R8 k_rec_y) ----
#define YMF(NT) { \
    short8 _f0 = *(const short8*)(Cl8 + ( 0 + NT)*512 + lane*8); \
    short8 _f1 = *(const short8*)(Cl8 + (16 + NT)*512 + lane*8); \
    C##NT = __builtin_amdgcn_mfma_f32_16x16x32_bf16(Af0, _f0, C##NT, 0, 0, 0); \
    C##NT = __builtin_amdgcn_mfma_f32_16x16x32_bf16(Af1, _f1, C##NT, 0, 0, 0); }
#define YST(NT) { \
    float* _yp = Y + ((size_t)(tb + TIL*16 + q*4) * 32 + b) * 256 + NT*16 + m; \
    _yp[0] = C##NT[0]; _yp[8192] = C##NT[1]; _yp[16384] = C##NT[2]; _yp[24576] = C##NT[3]; }
#define YTILE(TILARG) { \
    short8 Af0 = *(const short8*)(hw + (TILARG*16 + m)*72 +  0 + q*8); \
    short8 Af1 = *(const short8*)(hw + (TILARG*16 + m)*72 + 32 + q*8); \
    f32x4 C0={0,0,0,0},C1={0,0,0,0},C2={0,0,0,0},C3={0,0,0,0}, \
          C4={0,0,0,0},C5={0,0,0,0},C6={0,0,0,0},C7={0,0,0,0}, \
          C8={0,0,0,0},C9={0,0,0,0},C10={0,0,0,0},C11={0,0,0,0}, \
          C12={0,0,0,0},C13={0,0,0,0},C14={0,0,0,0},C15={0,0,0,0}; \
    YMF(0) YMF(1) YMF(2) YMF(3) YMF(4) YMF(5) YMF(6) YMF(7) \
    YMF(8) YMF(9) YMF(10) YMF(11) YMF(12) YMF(13) YMF(14) YMF(15) \
    YST(0) YST(1) YST(2) YST(3) YST(4) YST(5) YST(6) YST(7) \
    YST(8) YST(9) YST(10) YST(11) YST(12) YST(13) YST(14) YST(15) }

__global__ __launch_bounds__(256) void k_fused(
    const float* __restrict__ X, const float* __restrict__ Amat,
    const float* __restrict__ Bm, const float* __restrict__ Cm,
    float* __restrict__ hout, float* __restrict__ Y) {
  __shared__ __align__(16) unsigned int BCl[8192];            // 32 KB: B frags, later C frags
  __shared__ __align__(16) unsigned short bxl[4 * 48 * 72];   // 27 KB bx tiles (per wave)
  __shared__ __align__(16) unsigned short hlds[4 * 32 * 72];  // 18 KB h tiles (per wave)
  const int tid = threadIdx.x;
  if (blockIdx.x < 8) hout[blockIdx.x * 256 + tid] = 0.0f;    // h[0] = 0

#pragma unroll
  for (int ii = 0; ii < 32; ++ii) {          // stage B frags (verbatim from k_bx)
    const int i  = ii * 256 + tid;
    const int w  = i & 3, ln = (i >> 2) & 63, f = i >> 8;
    const int kc = f >> 2, nt = f & 3;
    const int row = nt * 16 + (ln & 15);
    const int col = kc * 32 + (ln >> 4) * 8 + w * 2;
    const float* p = Bm + row * 256 + col;
    BCl[i] = pack2bf(p[0], p[1]);
  }
  __syncthreads();

  const int lane = tid & 63;
  const int wv   = tid >> 6;
  const int wid  = blockIdx.x * 4 + wv;      // 0..2047
  const int c    = wid >> 5;                 // chunk 0..63
  const int b    = wid & 31;
  const int m    = lane & 15, q = lane >> 4;
  const int tout = c * CH;
  int base = tout - WARM; if (base < 0) base = 0;   // bx tile row 0 = timestep `base`
  unsigned short* bxw = bxl + wv * (48 * 72);
  const unsigned short* Bl8 = (const unsigned short*)BCl;

  // ---- bx phase: 48 timesteps x 64 latent for this (c,b), into LDS ----
  { XDECL
    FTILE(0) FTILE(1) FTILE(2) }
  __syncthreads();                           // all waves done reading B frags

#pragma unroll
  for (int ii = 0; ii < 32; ++ii) {          // stage C frags over B region
    const int i  = ii * 256 + tid;
    const int w  = i & 3, ln = (i >> 2) & 63, f = i >> 8;
    const int s  = f >> 4, nt = f & 15;
    const int row = nt * 16 + (ln & 15);
    const int col = s * 32 + (ln >> 4) * 8 + w * 2;
    const float* p = Cm + row * 64 + col;
    BCl[i] = pack2bf(p[0], p[1]);
  }
  __syncthreads();                           // C ready before any wave's y phase

  // ---- recurrence (identical to R8, u now from LDS at row stride 72) ----
  unsigned short* hw = hlds + wv * (32 * 72);
  const f32x4* Ap = (const f32x4*)(Amat + lane * 64);
  const f32x4 A0 = Ap[0],  A1 = Ap[1],  A2 = Ap[2],  A3 = Ap[3];
  const f32x4 A4 = Ap[4],  A5 = Ap[5],  A6 = Ap[6],  A7 = Ap[7];
  const f32x4 A8 = Ap[8],  A9 = Ap[9],  A10 = Ap[10], A11 = Ap[11];
  const f32x4 A12 = Ap[12], A13 = Ap[13], A14 = Ap[14], A15 = Ap[15];

  const int warmG = (tout - base) >> 2;      // 0 for c==0, else 4
  const unsigned short* up = bxw + lane;
  float c0 = bf2f(up[0]);
  float c1 = bf2f(up[72]);
  float c2 = bf2f(up[144]);
  float c3 = bf2f(up[216]);
  up += 288;

  float h = 0.0f;

#define RL(K) __uint_as_float(__builtin_amdgcn_readlane(hu, (K)))
#define G4(V, K) \
    h0 = fmaf(V[0], RL(K+0), h0); \
    h1 = fmaf(V[1], RL(K+1), h1); \
    h2 = fmaf(V[2], RL(K+2), h2); \
    h3 = fmaf(V[3], RL(K+3), h3);
#define STEP(UU) { \
    const unsigned int hu = __float_as_uint(h); \
    float h0 = (UU), h1 = 0.f, h2 = 0.f, h3 = 0.f; \
    G4(A0,  0) G4(A1,  4) G4(A2,  8) G4(A3, 12) \
    G4(A4, 16) G4(A5, 20) G4(A6, 24) G4(A7, 28) \
    G4(A8, 32) G4(A9, 36) G4(A10,40) G4(A11,44) \
    G4(A12,48) G4(A13,52) G4(A14,56) G4(A15,60) \
    h = (h0 + h1) + (h2 + h3); }

  for (int g = 0; g < warmG; ++g) {
    float n0 = bf2f(up[0]), n1 = bf2f(up[72]), n2 = bf2f(up[144]), n3 = bf2f(up[216]);
    up += 288;
    STEP(c0) STEP(c1) STEP(c2) STEP(c3)
    c0 = n0; c1 = n1; c2 = n2; c3 = n3;
  }

  float* hp = hout + (size_t)(tout + 1) * (NBAT * LAT) + b * LAT + lane;
  for (int g = 0; g < 7; ++g) {              // 7 groups with prefetch
    float n0 = bf2f(up[0]), n1 = bf2f(up[72]), n2 = bf2f(up[144]), n3 = bf2f(up[216]);
    up += 288;
    STEP(c0) hp[0]    = h;  hw[(g*4+0)*72 + lane] = f2bf(h);
    STEP(c1) hp[2048] = h;  hw[(g*4+1)*72 + lane] = f2bf(h);
    STEP(c2) hp[4096] = h;  hw[(g*4+2)*72 + lane] = f2bf(h);
    STEP(c3) hp[6144] = h;  hw[(g*4+3)*72 + lane] = f2bf(h);
    hp += 8192;
    c0 = n0; c1 = n1; c2 = n2; c3 = n3;
  }
  // last group peeled: no prefetch (avoids LDS read past the 48-row tile)
  STEP(c0) hp[0]    = h;  hw[28*72 + lane] = f2bf(h);
  STEP(c1) hp[2048] = h;  hw[29*72 + lane] = f2bf(h);
  STEP(c2) hp[4096] = h;  hw[30*72 + lane] = f2bf(h);
  STEP(c3) hp[6144] = h;  hw[31*72 + lane] = f2bf(h);
#undef STEP
#undef G4
#undef RL

  // ---- y phase: same-wave LDS RAW (lgkmcnt only, no barrier needed) ----
  const unsigned short* Cl8 = (const unsigned short*)BCl;
  const int tb = tout;
  { const int TIL = 0; YTILE(0) }
  { const int TIL = 1; YTILE(1) }
}

extern "C" void kernel_launch(void* const* d_in, const int* in_sizes, int n_in,
                              void* d_out, int out_size, void* d_ws, size_t ws_size,
                              hipStream_t stream) {
  const float* X  = (const float*)d_in[0];   // x [2048][32][256] fp32
  const float* Am = (const float*)d_in[1];   // A [64][64]
  const float* Bm = (const float*)d_in[2];   // B [64][256]
  const float* Cm = (const float*)d_in[3];   // C [256][64]

  float* Yout = (float*)d_out;                          // [2048*32*256] fp32
  float* Hout = Yout + (size_t)SEQ * NBAT * DOUT;       // [2049*32*64] fp32
  (void)d_ws; (void)ws_size;                            // d_ws no longer used

  k_fused<<<512, 256, 0, stream>>>(X, Am, Bm, Cm, Hout, Yout);
}